// Round 1
// baseline (89.641 us; speedup 1.0000x reference)
//
#include <hip/hip_runtime.h>

// EnhancedVectorQuantizer: z (65536,64) f32, codebook_w (64,16) f32
// outputs: z_q_sg (65536*64) f32 | vq_loss (1) f32 | indices (65536*64) as f32
constexpr int B_SZ = 65536;
constexpr int D_SZ = 64;
constexpr int K_SZ = 16;
constexpr int N_ELEM = B_SZ * D_SZ;   // 4194304
constexpr int N_VEC  = N_ELEM / 4;    // 1048576
constexpr int NBLOCKS  = 1024;
constexpr int NTHREADS = 256;
// 1/(B*D) + 0.25/B = 2^-22 + 2^-18 = 17*2^-22, exact in fp32
constexpr float LOSS_SCALE = 4.0531158447265625e-06f;

__global__ __launch_bounds__(NTHREADS, 4)
void vq_main(const float* __restrict__ z, const float* __restrict__ cb,
             float* __restrict__ zq, float* __restrict__ idx,
             float* __restrict__ partials)
{
    const int t    = threadIdx.x;
    const int gtid = blockIdx.x * NTHREADS + t;
    const int stride = NBLOCKS * NTHREADS;          // multiple of 16 -> d0 invariant
    const int d0 = 4 * (gtid & 15);                 // this thread's first codebook row

    // Load this thread's 4 codebook rows (d0..d0+3, 16 entries each) into registers.
    float c[4][K_SZ];
#pragma unroll
    for (int j = 0; j < 4; ++j) {
        const float4* row = (const float4*)(cb + (d0 + j) * K_SZ);
#pragma unroll
        for (int q = 0; q < 4; ++q) {
            float4 r = row[q];
            c[j][4*q+0] = r.x; c[j][4*q+1] = r.y;
            c[j][4*q+2] = r.z; c[j][4*q+3] = r.w;
        }
    }

    float local = 0.0f;
    for (int v = gtid; v < N_VEC; v += stride) {
        float4 zv = ((const float4*)z)[v];
        float zs[4] = {zv.x, zv.y, zv.z, zv.w};
        float qv[4], kf[4];
#pragma unroll
        for (int j = 0; j < 4; ++j) {
            // argmin_k (z - c_k)^2, first-min tie-break == np.argmin, fp32 exact
            float diff = zs[j] - c[j][0];
            float best = diff * diff;
            float bc = c[j][0];
            int bk = 0;
#pragma unroll
            for (int k = 1; k < K_SZ; ++k) {
                float dk = zs[j] - c[j][k];
                float dist = dk * dk;
                if (dist < best) { best = dist; bk = k; bc = c[j][k]; }
            }
            qv[j] = bc;
            kf[j] = (float)bk;
            local += best;   // (z - z_q)^2 of the winner, exact same value
        }
        ((float4*)zq)[v] = make_float4(qv[0], qv[1], qv[2], qv[3]);
        // idx region is 4B-aligned only (odd float offset) -> scalar dword stores;
        // the 4 stores jointly cover full 64B lines, so HBM writes stay ideal.
        const int e = 4 * v;
        idx[e+0] = kf[0]; idx[e+1] = kf[1]; idx[e+2] = kf[2]; idx[e+3] = kf[3];
    }

    // block reduction of loss partial
#pragma unroll
    for (int off = 32; off > 0; off >>= 1)
        local += __shfl_down(local, off, 64);
    __shared__ float s[NTHREADS / 64];
    if ((t & 63) == 0) s[t >> 6] = local;
    __syncthreads();
    if (t == 0) {
        float bsum = 0.f;
#pragma unroll
        for (int w = 0; w < NTHREADS / 64; ++w) bsum += s[w];
        partials[blockIdx.x] = bsum;
    }
}

__global__ __launch_bounds__(256)
void vq_reduce(const float* __restrict__ partials, float* __restrict__ loss)
{
    const int t = threadIdx.x;
    float local = 0.0f;
    for (int i = t; i < NBLOCKS; i += 256) local += partials[i];
#pragma unroll
    for (int off = 32; off > 0; off >>= 1)
        local += __shfl_down(local, off, 64);
    __shared__ float s[4];
    if ((t & 63) == 0) s[t >> 6] = local;
    __syncthreads();
    if (t == 0) loss[0] = (s[0] + s[1] + s[2] + s[3]) * LOSS_SCALE;
}

extern "C" void kernel_launch(void* const* d_in, const int* in_sizes, int n_in,
                              void* d_out, int out_size, void* d_ws, size_t ws_size,
                              hipStream_t stream)
{
    const float* z  = (const float*)d_in[0];
    const float* cb = (const float*)d_in[1];
    float* out  = (float*)d_out;
    float* zq   = out;                 // 4194304 floats
    float* loss = out + N_ELEM;        // 1 float
    float* idx  = out + N_ELEM + 1;    // 4194304 floats (indices as f32)
    float* partials = (float*)d_ws;    // NBLOCKS floats

    vq_main<<<NBLOCKS, NTHREADS, 0, stream>>>(z, cb, zq, idx, partials);
    vq_reduce<<<1, 256, 0, stream>>>(partials, loss);
}

// Round 2
// 84.043 us; speedup vs baseline: 1.0666x; 1.0666x over previous
//
#include <hip/hip_runtime.h>

// EnhancedVectorQuantizer: z (65536,64) f32, codebook_w (64,16) f32
// outputs: z_q_sg (4194304) f32 | vq_loss (1) f32 | indices (4194304) as f32
constexpr int B_SZ = 65536;
constexpr int D_SZ = 64;
constexpr int K_SZ = 16;
constexpr int N_ELEM = B_SZ * D_SZ;   // 4194304
constexpr int NBLOCKS  = 4096;        // 4096 blocks * 1024 elem/block = N_ELEM exactly
constexpr int NTHREADS = 256;
// 1/(B*D) + 0.25/B = 2^-22 + 2^-18 = 17*2^-22, exact in fp32
constexpr float LOSS_SCALE = 4.0531158447265625e-06f;

// Mapping: block b owns elements [b*1024, (b+1)*1024). Wave w (t>>6) owns
// [b*1024 + w*256, +256); element e = wave_base + j*64 + lane, j=0..3.
// Since wave_base % 64 == 0 and D == 64: d = e & 63 == lane. Each lane
// needs exactly ONE codebook row -> 16 VGPRs of codebook, and every
// load/store is scalar-dword with consecutive lanes (fully coalesced;
// the idx region's odd base offset no longer matters).
__global__ __launch_bounds__(NTHREADS)
void vq_main(const float* __restrict__ z, const float* __restrict__ cb,
             float* __restrict__ zq, float* __restrict__ idx,
             float* __restrict__ partials)
{
    const int t    = threadIdx.x;
    const int lane = t & 63;
    const int wave_base = blockIdx.x * 1024 + (t >> 6) * 256;

    // This lane's codebook row: cb[lane*16 + k], k=0..15 (4 KB total, L1-hot)
    float c[K_SZ];
    const float4* crow = (const float4*)(cb + lane * K_SZ);
#pragma unroll
    for (int q = 0; q < 4; ++q) {
        float4 r = crow[q];
        c[4*q+0] = r.x; c[4*q+1] = r.y; c[4*q+2] = r.z; c[4*q+3] = r.w;
    }

    // Load all 4 z values up front for ILP (independent, coalesced).
    float zs[4];
#pragma unroll
    for (int j = 0; j < 4; ++j)
        zs[j] = __builtin_nontemporal_load(z + wave_base + j * 64 + lane);

    float local = 0.0f;
#pragma unroll
    for (int j = 0; j < 4; ++j) {
        const int e = wave_base + j * 64 + lane;
        // argmin_k (z - c_k)^2, strict-< first-min == np.argmin, fp32 exact
        float diff = zs[j] - c[0];
        float best = diff * diff;
        float bc   = c[0];
        int   bk   = 0;
#pragma unroll
        for (int k = 1; k < K_SZ; ++k) {
            float dk   = zs[j] - c[k];
            float dist = dk * dk;
            if (dist < best) { best = dist; bk = k; bc = c[k]; }
        }
        local += best;  // winner's (z - z_q)^2, exact same value as reference
        __builtin_nontemporal_store(bc, zq + e);
        __builtin_nontemporal_store((float)bk, idx + e);
    }

    // block reduction of loss partial
#pragma unroll
    for (int off = 32; off > 0; off >>= 1)
        local += __shfl_down(local, off, 64);
    __shared__ float s[NTHREADS / 64];
    if ((t & 63) == 0) s[t >> 6] = local;
    __syncthreads();
    if (t == 0) {
        float bsum = 0.f;
#pragma unroll
        for (int w = 0; w < NTHREADS / 64; ++w) bsum += s[w];
        partials[blockIdx.x] = bsum;
    }
}

__global__ __launch_bounds__(256)
void vq_reduce(const float* __restrict__ partials, float* __restrict__ loss)
{
    const int t = threadIdx.x;
    float local = 0.0f;
#pragma unroll
    for (int i = 0; i < NBLOCKS / 256; ++i)
        local += partials[i * 256 + t];
#pragma unroll
    for (int off = 32; off > 0; off >>= 1)
        local += __shfl_down(local, off, 64);
    __shared__ float s[4];
    if ((t & 63) == 0) s[t >> 6] = local;
    __syncthreads();
    if (t == 0) loss[0] = (s[0] + s[1] + s[2] + s[3]) * LOSS_SCALE;
}

extern "C" void kernel_launch(void* const* d_in, const int* in_sizes, int n_in,
                              void* d_out, int out_size, void* d_ws, size_t ws_size,
                              hipStream_t stream)
{
    const float* z  = (const float*)d_in[0];
    const float* cb = (const float*)d_in[1];
    float* out  = (float*)d_out;
    float* zq   = out;                 // 4194304 floats
    float* loss = out + N_ELEM;        // 1 float
    float* idx  = out + N_ELEM + 1;    // 4194304 floats (indices as f32)
    float* partials = (float*)d_ws;    // NBLOCKS floats

    vq_main<<<NBLOCKS, NTHREADS, 0, stream>>>(z, cb, zq, idx, partials);
    vq_reduce<<<1, 256, 0, stream>>>(partials, loss);
}